// Round 5
// baseline (186.919 us; speedup 1.0000x reference)
//
#include <hip/hip_runtime.h>

// Soft-label cross entropy, fused single pass (best-known structure, round 2):
//   loss = mean_i [ (m_i + log(sum_j exp(p_ij - m_i))) * (sum_j t_ij) - sum_j t_ij*p_ij ]
// One wave per row. C=1000 compile-time -> 250 float4/row; lanes hold p in
// registers across the max->exp phases; t streamed in phase 2 (short live
// ranges, no spill under the 64-VGPR cap). Sum_j t*p is accumulated
// lane-locally and reduced once per wave. Non-temporal loads (zero reuse).
// Two kernels: grid partials -> 1-block reduce. (Fused last-block-done was
// tried in rounds 3-4: net -7..-86 us. Dispatch #2 is cheaper than the
// cross-XCD visibility machinery.)

typedef float f32x4 __attribute__((ext_vector_type(4)));

#define WAVES_PER_BLOCK 4
#define BLOCK_THREADS 256
#define NBLOCKS 2048
#define CCONST 1000
#define C4CONST (CCONST / 4)   // 250

__global__ __launch_bounds__(BLOCK_THREADS, 8)   // pin 8 waves/SIMD (VGPR<=64)
void ce_rows_kernel(const float* __restrict__ pred,
                    const float* __restrict__ targ,
                    float* __restrict__ partial,
                    int nrows) {
    const int lane = threadIdx.x & 63;
    const int wid  = threadIdx.x >> 6;
    const int waves_total = gridDim.x * WAVES_PER_BLOCK;
    const int wave_global = blockIdx.x * WAVES_PER_BLOCK + wid;

    float acc_lse = 0.0f;  // wave-uniform after reduces: sum of lse_row * st_row
    float acc_tp  = 0.0f;  // lane-local: sum of t*p, reduced once at the end

    for (int row = wave_global; row < nrows; row += waves_total) {
        const f32x4* __restrict__ p4 = (const f32x4*)(pred + (size_t)row * CCONST);
        const f32x4* __restrict__ t4 = (const f32x4*)(targ + (size_t)row * CCONST);

        // Phase 1: load p row into registers (non-temporal), wave max.
        // it=0..2: idx = lane + it*64 <= 191 < 250, always active.
        // it=3: idx in [192,255], lanes with idx >= 250 masked (compile-time C).
        f32x4 pv[4];
        float m = -3.0e38f;
        #pragma unroll
        for (int it = 0; it < 4; ++it) {
            int idx = lane + it * 64;
            if (idx < C4CONST) pv[it] = __builtin_nontemporal_load(p4 + idx);
        }
        #pragma unroll
        for (int it = 0; it < 4; ++it) {
            int idx = lane + it * 64;
            if (idx < C4CONST)
                m = fmaxf(m, fmaxf(fmaxf(pv[it][0], pv[it][1]),
                                   fmaxf(pv[it][2], pv[it][3])));
        }
        #pragma unroll
        for (int off = 32; off > 0; off >>= 1)
            m = fmaxf(m, __shfl_xor(m, off, 64));

        // Phase 2: stream t (short live ranges -- no spill), accumulate.
        float se = 0.0f, st = 0.0f;
        #pragma unroll
        for (int it = 0; it < 4; ++it) {
            int idx = lane + it * 64;
            if (idx < C4CONST) {
                f32x4 t = __builtin_nontemporal_load(t4 + idx);
                f32x4 p = pv[it];
                se += __expf(p[0] - m) + __expf(p[1] - m)
                    + __expf(p[2] - m) + __expf(p[3] - m);
                st += (t[0] + t[1]) + (t[2] + t[3]);
                acc_tp += t[0]*p[0] + t[1]*p[1] + t[2]*p[2] + t[3]*p[3];
            }
        }
        #pragma unroll
        for (int off = 32; off > 0; off >>= 1) {
            se += __shfl_xor(se, off, 64);
            st += __shfl_xor(st, off, 64);
        }
        acc_lse += (m + __logf(se)) * st;
    }

    // Deferred reduce of lane-local t*p accumulation.
    #pragma unroll
    for (int off = 32; off > 0; off >>= 1)
        acc_tp += __shfl_xor(acc_tp, off, 64);

    float wave_sum = acc_lse - acc_tp;

    __shared__ float lds[WAVES_PER_BLOCK];
    if (lane == 0) lds[wid] = wave_sum;
    __syncthreads();
    if (threadIdx.x == 0) {
        float s = 0.0f;
        #pragma unroll
        for (int i = 0; i < WAVES_PER_BLOCK; ++i) s += lds[i];
        partial[blockIdx.x] = s;
    }
}

__global__ __launch_bounds__(256)
void ce_reduce_kernel(const float* __restrict__ partial, int n,
                      float* __restrict__ out, float inv_n) {
    __shared__ float lds[256];
    float s = 0.0f;
    for (int i = threadIdx.x; i < n; i += 256) s += partial[i];
    lds[threadIdx.x] = s;
    __syncthreads();
    #pragma unroll
    for (int stride = 128; stride > 0; stride >>= 1) {
        if ((int)threadIdx.x < stride) lds[threadIdx.x] += lds[threadIdx.x + stride];
        __syncthreads();
    }
    if (threadIdx.x == 0) out[0] = lds[0] * inv_n;
}

extern "C" void kernel_launch(void* const* d_in, const int* in_sizes, int n_in,
                              void* d_out, int out_size, void* d_ws, size_t ws_size,
                              hipStream_t stream) {
    const float* pred = (const float*)d_in[0];
    const float* targ = (const float*)d_in[1];
    float* out = (float*)d_out;

    const int N = in_sizes[0] / CCONST;   // 131072

    int nblocks = NBLOCKS;                // 2048 x 4 waves = 8192 waves = 16 rows/wave
    if ((size_t)nblocks * sizeof(float) > ws_size)
        nblocks = (int)(ws_size / sizeof(float));
    if (nblocks < 1) nblocks = 1;

    float* partial = (float*)d_ws;

    ce_rows_kernel<<<nblocks, BLOCK_THREADS, 0, stream>>>(pred, targ, partial, N);
    ce_reduce_kernel<<<1, 256, 0, stream>>>(partial, nblocks, out, 1.0f / (float)N);
}

// Round 6
// 174.168 us; speedup vs baseline: 1.0732x; 1.0732x over previous
//
#include <hip/hip_runtime.h>

// Soft-label cross entropy, fused single pass:
//   loss = mean_i [ (m_i + log(sum_j exp(p_ij - m_i))) * (sum_j t_ij) - sum_j t_ij*p_ij ]
// One wave per row (C=1000 = 250 float4). p held in registers between the
// max phase and the exp phase. Sum_j t*p is accumulated lane-locally across
// all rows and reduced ONCE per wave at the end (it doesn't need the per-row
// lse), saving 6 shuffles/row. Non-temporal loads: streams have zero reuse.
//
// NOTE: C is deliberately a RUNTIME parameter. Making it compile-time (R5)
// let the compiler hoist phase-2's t-loads above their uses, stretching live
// ranges under the 64-VGPR cap -> 175 -> 187 us regression. Same mechanism
// as R3's up-front t-loads (261 us). The opaque C keeps the load-use
// schedule tight. Fused last-block-done reduction (R3/R4) also regressed
// (cross-XCD visibility machinery > 2nd-dispatch cost); two kernels it is.

typedef float f32x4 __attribute__((ext_vector_type(4)));

#define WAVES_PER_BLOCK 4
#define BLOCK_THREADS 256
#define NBLOCKS 2048

__global__ __launch_bounds__(BLOCK_THREADS, 8)   // pin 8 waves/SIMD (VGPR<=64)
void ce_rows_kernel(const float* __restrict__ pred,
                    const float* __restrict__ targ,
                    float* __restrict__ partial,
                    int nrows, int C) {
    const int lane = threadIdx.x & 63;
    const int wid  = threadIdx.x >> 6;
    const int waves_total = gridDim.x * WAVES_PER_BLOCK;
    const int wave_global = blockIdx.x * WAVES_PER_BLOCK + wid;
    const int C4 = C >> 2;   // 250

    float acc_lse = 0.0f;  // wave-uniform: sum of lse_row * st_row
    float acc_tp  = 0.0f;  // lane-local: sum of t*p over all elements seen

    for (int row = wave_global; row < nrows; row += waves_total) {
        const f32x4* __restrict__ p4 = (const f32x4*)(pred + (size_t)row * C);
        const f32x4* __restrict__ t4 = (const f32x4*)(targ + (size_t)row * C);

        // Phase 1: load p row into registers (non-temporal), lane max
        f32x4 pv[4];
        float m = -3.0e38f;
        #pragma unroll
        for (int it = 0; it < 4; ++it) {
            int idx = lane + it * 64;
            if (idx < C4) pv[it] = __builtin_nontemporal_load(p4 + idx);
        }
        #pragma unroll
        for (int it = 0; it < 4; ++it) {
            int idx = lane + it * 64;
            if (idx < C4)
                m = fmaxf(m, fmaxf(fmaxf(pv[it][0], pv[it][1]),
                                   fmaxf(pv[it][2], pv[it][3])));
        }
        #pragma unroll
        for (int off = 32; off > 0; off >>= 1)
            m = fmaxf(m, __shfl_xor(m, off, 64));

        // Phase 2: stream t (non-temporal), accumulate expsum / st / t*p
        float se = 0.0f, st = 0.0f;
        #pragma unroll
        for (int it = 0; it < 4; ++it) {
            int idx = lane + it * 64;
            if (idx < C4) {
                f32x4 t = __builtin_nontemporal_load(t4 + idx);
                f32x4 p = pv[it];
                se += __expf(p[0] - m) + __expf(p[1] - m)
                    + __expf(p[2] - m) + __expf(p[3] - m);
                st += (t[0] + t[1]) + (t[2] + t[3]);
                acc_tp += t[0]*p[0] + t[1]*p[1] + t[2]*p[2] + t[3]*p[3];
            }
        }
        #pragma unroll
        for (int off = 32; off > 0; off >>= 1) {
            se += __shfl_xor(se, off, 64);
            st += __shfl_xor(st, off, 64);
        }
        acc_lse += (m + __logf(se)) * st;
    }

    // Deferred reduce of lane-local t*p accumulation
    #pragma unroll
    for (int off = 32; off > 0; off >>= 1)
        acc_tp += __shfl_xor(acc_tp, off, 64);

    float wave_sum = acc_lse - acc_tp;   // both wave-uniform now

    __shared__ float lds[WAVES_PER_BLOCK];
    if (lane == 0) lds[wid] = wave_sum;
    __syncthreads();
    if (threadIdx.x == 0) {
        float s = 0.0f;
        #pragma unroll
        for (int i = 0; i < WAVES_PER_BLOCK; ++i) s += lds[i];
        partial[blockIdx.x] = s;
    }
}

__global__ __launch_bounds__(256)
void ce_reduce_kernel(const float* __restrict__ partial, int n,
                      float* __restrict__ out, float inv_n) {
    __shared__ float lds[256];
    float s = 0.0f;
    for (int i = threadIdx.x; i < n; i += 256) s += partial[i];
    lds[threadIdx.x] = s;
    __syncthreads();
    #pragma unroll
    for (int stride = 128; stride > 0; stride >>= 1) {
        if ((int)threadIdx.x < stride) lds[threadIdx.x] += lds[threadIdx.x + stride];
        __syncthreads();
    }
    if (threadIdx.x == 0) out[0] = lds[0] * inv_n;
}

extern "C" void kernel_launch(void* const* d_in, const int* in_sizes, int n_in,
                              void* d_out, int out_size, void* d_ws, size_t ws_size,
                              hipStream_t stream) {
    const float* pred = (const float*)d_in[0];
    const float* targ = (const float*)d_in[1];
    float* out = (float*)d_out;

    const int C = 1000;
    const int N = in_sizes[0] / C;   // 131072

    int nblocks = NBLOCKS;           // 2048 blocks x 4 waves = 8192 waves = full residency
    if ((size_t)nblocks * sizeof(float) > ws_size)
        nblocks = (int)(ws_size / sizeof(float));
    if (nblocks < 1) nblocks = 1;

    float* partial = (float*)d_ws;

    ce_rows_kernel<<<nblocks, BLOCK_THREADS, 0, stream>>>(pred, targ, partial, N, C);
    ce_reduce_kernel<<<1, 256, 0, stream>>>(partial, nblocks, out, 1.0f / (float)N);
}